// Round 7
// baseline (189.372 us; speedup 1.0000x reference)
//
#include <hip/hip_runtime.h>

// Problem constants (fixed by reference setup_inputs)
#define B_N 8192
#define D_N 256
#define N_N 2048
#define K_N 512
#define T_N 8
#define MAIN_BLOCKS 1296

using short8  = __attribute__((ext_vector_type(8))) short;
using floatx4 = __attribute__((ext_vector_type(4))) float;

// ---------------------------------------------------------------------------
// Workspace layout (float units):
//  acc     = ws + 0      [16]   0=ju 1=jt 2=ortho 3=msum 4=done-counter(u32)
//  cb      = ws + 16     [8192]
//  nn2     = ws + 8208   [2048]
//  fn2     = ws + 10256  [512]
//  selc    = ws + 10768  [8192*8]   (m_t + td - vn2 per selected t)
//  seli    = (int*)(ws + 76304)  [8192*8]
//  vhat_bf = (ushort*)(ws + 141840)  [8192*256]  (16B aligned)
//  neg_bf  = vhat_bf + 8192*256      [2048*256]
//  F_bf    = neg_bf + 2048*256       [512*256]
// ---------------------------------------------------------------------------

__device__ __forceinline__ float wave_reduce_sum(float x) {
  #pragma unroll
  for (int off = 32; off > 0; off >>= 1) x += __shfl_down(x, off, 64);
  return x;
}

__device__ __forceinline__ unsigned int f2bf(float x) {
  unsigned u = __float_as_uint(x);
  return (u + 0x7fffu + ((u >> 16) & 1u)) >> 16;
}

__device__ __forceinline__ unsigned int pack2bf(float x, float y) {
  return f2bf(x) | (f2bf(y) << 16);
}

// async global->LDS, 16 bytes per lane; LDS dest is wave-uniform base + lane*16
__device__ __forceinline__ void gload16(const unsigned short* g, unsigned short* l) {
  __builtin_amdgcn_global_load_lds(
      (const __attribute__((address_space(1))) unsigned int*)g,
      (__attribute__((address_space(3))) unsigned int*)l, 16, 0, 0);
}

// compare-swap keeping (val,idx) pairs together
#define CSWAP(a, b)                                              \
  {                                                              \
    bool sw_ = sv[a] > sv[b];                                    \
    float tv_ = sw_ ? sv[a] : sv[b];                             \
    sv[a] = sw_ ? sv[b] : sv[a];                                 \
    sv[b] = tv_;                                                 \
    int ti_ = sw_ ? si[a] : si[b];                               \
    si[a] = sw_ ? si[b] : si[a];                                 \
    si[b] = ti_;                                                 \
  }

// --- prep: stats + bf16 conversion + bottom-8 selection + acc zeroing -------
// one row per wave; rows [0,B)=vhat(+v,+g-selection), [B,B+N)=neg, [B+N,..)=F
__global__ __launch_bounds__(256) void prep_kernel(
    const float* __restrict__ v, const float* __restrict__ vhat,
    const float* __restrict__ neg, const float* __restrict__ F,
    const float* __restrict__ g,
    unsigned short* __restrict__ vhat_bf, unsigned short* __restrict__ neg_bf,
    unsigned short* __restrict__ F_bf,
    float* __restrict__ cb, float* __restrict__ nn2, float* __restrict__ fn2,
    float* __restrict__ selc, int* __restrict__ seli,
    float* __restrict__ acc) {
  int lane = threadIdx.x & 63;
  int row = (blockIdx.x << 2) + (threadIdx.x >> 6);
  if (blockIdx.x == 0 && threadIdx.x < 16) acc[threadIdx.x] = 0.0f;
  if (row < B_N) {
    const float4 a = *(const float4*)(vhat + (size_t)row * D_N + lane * 4);
    const float4 b = *(const float4*)(v + (size_t)row * D_N + lane * 4);
    float dx = a.x - b.x, dy = a.y - b.y, dz = a.z - b.z, dw = a.w - b.w;
    float t = dx * dx + dy * dy + dz * dz + dw * dw;
    float n = a.x * a.x + a.y * a.y + a.z * a.z + a.w * a.w;
    uint2 p;
    p.x = pack2bf(a.x, a.y);
    p.y = pack2bf(a.z, a.w);
    *(uint2*)(vhat_bf + (size_t)row * D_N + lane * 4) = p;
    t = wave_reduce_sum(t);
    n = wave_reduce_sum(n);
    if (lane == 0) cb[row] = 1.0f + t - n;
    // ---- bottom-8-of-512 selection on g[row] ----
    const float* grow = g + (size_t)row * K_N;
    float sv[8];
    int si[8];
    {
      float4 g0 = *(const float4*)(grow + lane * 8);
      float4 g1 = *(const float4*)(grow + lane * 8 + 4);
      sv[0] = g0.x; sv[1] = g0.y; sv[2] = g0.z; sv[3] = g0.w;
      sv[4] = g1.x; sv[5] = g1.y; sv[6] = g1.z; sv[7] = g1.w;
      #pragma unroll
      for (int j = 0; j < 8; ++j) si[j] = lane * 8 + j;
    }
    // Batcher odd-even mergesort, n=8 (19 comparators) -> ascending
    CSWAP(0,1) CSWAP(2,3) CSWAP(4,5) CSWAP(6,7)
    CSWAP(0,2) CSWAP(1,3) CSWAP(4,6) CSWAP(5,7)
    CSWAP(1,2) CSWAP(5,6)
    CSWAP(0,4) CSWAP(1,5) CSWAP(2,6) CSWAP(3,7)
    CSWAP(2,4) CSWAP(3,5)
    CSWAP(1,2) CSWAP(3,4) CSWAP(5,6)
    // 6 butterfly merge rounds: keep lowest 8 of (mine ++ partner)
    #pragma unroll
    for (int rr = 0; rr < 6; ++rr) {
      const int msk = 1 << rr;
      float pv[8];
      int pi[8];
      #pragma unroll
      for (int j = 0; j < 8; ++j) {
        pv[j] = __shfl_xor(sv[j], msk, 64);
        pi[j] = __shfl_xor(si[j], msk, 64);
      }
      float cv[8];
      int ci[8];
      #pragma unroll
      for (int j = 0; j < 8; ++j) {
        bool mine = sv[j] <= pv[7 - j];
        cv[j] = mine ? sv[j] : pv[7 - j];
        ci[j] = mine ? si[j] : pi[7 - j];
      }
      #pragma unroll
      for (int j = 0; j < 8; ++j) { sv[j] = cv[j]; si[j] = ci[j]; }
      // bitonic -> sorted (distances 4,2,1)
      CSWAP(0,4) CSWAP(1,5) CSWAP(2,6) CSWAP(3,7)
      CSWAP(0,2) CSWAP(1,3) CSWAP(4,6) CSWAP(5,7)
      CSWAP(0,1) CSWAP(2,3) CSWAP(4,5) CSWAP(6,7)
    }
    // every lane now holds the global bottom-8 (sorted).
    float gsum = 1e-10f;
    #pragma unroll
    for (int t8 = 0; t8 < T_N; ++t8) gsum += sv[t8];
    if (lane == 0) {
      float base = t - n;  // td - vn2 (valid on lane 0)
      #pragma unroll
      for (int t8 = 0; t8 < T_N; ++t8) {
        float gt = sv[t8] / gsum;
        float mt = (1.0f - gt) * (1.0f - gt);
        selc[(size_t)row * T_N + t8] = mt + base;
        seli[(size_t)row * T_N + t8] = si[t8];
      }
    }
  } else if (row < B_N + N_N) {
    int r = row - B_N;
    const float4 a = *(const float4*)(neg + (size_t)r * D_N + lane * 4);
    float n = a.x * a.x + a.y * a.y + a.z * a.z + a.w * a.w;
    uint2 p;
    p.x = pack2bf(a.x, a.y);
    p.y = pack2bf(a.z, a.w);
    *(uint2*)(neg_bf + (size_t)r * D_N + lane * 4) = p;
    n = wave_reduce_sum(n);
    if (lane == 0) nn2[r] = n;
  } else {
    int r = row - (B_N + N_N);
    const float4 a = *(const float4*)(F + (size_t)r * D_N + lane * 4);
    float n = a.x * a.x + a.y * a.y + a.z * a.z + a.w * a.w;
    uint2 p;
    p.x = pack2bf(a.x, a.y);
    p.y = pack2bf(a.z, a.w);
    *(uint2*)(F_bf + (size_t)r * D_N + lane * 4) = p;
    n = wave_reduce_sum(n);
    if (lane == 0) fn2[r] = n;
  }
}

// --- main: ju [0,1024) | ortho [1024,1040) | W+jt [1040,1296) + finalize ----
__global__ __launch_bounds__(256) void main_kernel(
    const unsigned short* __restrict__ vhat_bf, const unsigned short* __restrict__ neg_bf,
    const unsigned short* __restrict__ F_bf,
    const float* __restrict__ cb, const float* __restrict__ nn2,
    const float* __restrict__ fn2, const int* __restrict__ mask,
    const float* __restrict__ selc, const int* __restrict__ seli,
    float* __restrict__ acc, float* __restrict__ out) {
  __shared__ __align__(16) unsigned char smem[16384];
  const int bx = blockIdx.x;
  const int tid = threadIdx.x;
  const int lane = tid & 63;
  const int wave = tid >> 6;

  unsigned short* AsU = (unsigned short*)smem;  // 128 rows x 32 k (bf16)
  unsigned short* BsU = AsU + 4096;
  int r0, c0;
  const unsigned short *Abase, *Bbase;
  int seg;  // 0=ju 1=ortho 2=W+jt
  if (bx < 1024) {
    seg = 0;
    r0 = (bx >> 4) * 128;
    c0 = (bx & 15) * 128;
    Abase = vhat_bf;
    Bbase = neg_bf;
  } else if (bx < 1040) {
    seg = 1;
    int o = bx - 1024;
    r0 = (o >> 2) * 128;
    c0 = (o & 3) * 128;
    Abase = F_bf;
    Bbase = F_bf;
  } else {
    seg = 2;
    int o = bx - 1040;
    r0 = (o >> 2) * 128;
    c0 = (o & 3) * 128;
    Abase = vhat_bf;
    Bbase = F_bf;
  }
  const int wx = wave & 1, wy = wave >> 1;

  // staging: LDS slot (r, c_slot) holds global 16B-chunk c_g = c_slot ^ ((r>>1)&3)
  const int c_slot = lane & 3;
  const int rA0 = wave * 32 + (lane >> 2);
  const int rA1 = rA0 + 16;
  const int cg0 = c_slot ^ ((rA0 >> 1) & 3);
  const int cg1 = c_slot ^ ((rA1 >> 1) & 3);
  const unsigned short* gA0 = Abase + (size_t)(r0 + rA0) * D_N + cg0 * 8;
  const unsigned short* gA1 = Abase + (size_t)(r0 + rA1) * D_N + cg1 * 8;
  const unsigned short* gB0 = Bbase + (size_t)(c0 + rA0) * D_N + cg0 * 8;
  const unsigned short* gB1 = Bbase + (size_t)(c0 + rA1) * D_N + cg1 * 8;
  unsigned short* lA0 = AsU + wave * 1024 + lane * 8;
  unsigned short* lA1 = lA0 + 512;
  unsigned short* lB0 = BsU + wave * 1024 + lane * 8;
  unsigned short* lB1 = lB0 + 512;

  // fragment LDS offsets (constant over k-loop)
  const int fr = lane & 15;
  const int fc = lane >> 4;
  int aoff[4], boff[4];
  #pragma unroll
  for (int i = 0; i < 4; ++i) {
    int ra = wy * 64 + i * 16 + fr;
    aoff[i] = ra * 32 + (fc ^ ((ra >> 1) & 3)) * 8;
    int rb = wx * 64 + i * 16 + fr;
    boff[i] = rb * 32 + (fc ^ ((rb >> 1) & 3)) * 8;
  }

  floatx4 acc4[4][4];
  #pragma unroll
  for (int i = 0; i < 4; ++i)
    #pragma unroll
    for (int j = 0; j < 4; ++j)
      acc4[i][j] = floatx4{0.0f, 0.0f, 0.0f, 0.0f};

  for (int k0 = 0; k0 < D_N; k0 += 32) {
    __syncthreads();
    gload16(gA0 + k0, lA0);
    gload16(gA1 + k0, lA1);
    gload16(gB0 + k0, lB0);
    gload16(gB1 + k0, lB1);
    __syncthreads();
    short8 af[4], bf[4];
    #pragma unroll
    for (int i = 0; i < 4; ++i) af[i] = *(const short8*)(AsU + aoff[i]);
    #pragma unroll
    for (int j = 0; j < 4; ++j) bf[j] = *(const short8*)(BsU + boff[j]);
    #pragma unroll
    for (int i = 0; i < 4; ++i)
      #pragma unroll
      for (int j = 0; j < 4; ++j)
        acc4[i][j] = __builtin_amdgcn_mfma_f32_16x16x32_bf16(af[i], bf[j], acc4[i][j], 0, 0, 0);
  }

  // epilogue: C/D layout col=lane&15 (j), row=(lane>>4)*4+reg (i)
  float* red = (float*)smem;
  if (seg == 0) {
    float nns[4];
    #pragma unroll
    for (int j = 0; j < 4; ++j)
      nns[j] = nn2[c0 + wx * 64 + j * 16 + (lane & 15)];
    float lsum = 0.0f;
    #pragma unroll
    for (int i = 0; i < 4; ++i) {
      #pragma unroll
      for (int r = 0; r < 4; ++r) {
        int b = r0 + wy * 64 + i * 16 + (lane >> 4) * 4 + r;
        float cbb = cb[b];
        float mf = (mask[b] != 0) ? 1.0f : 0.0f;
        float rs = 0.0f;
        #pragma unroll
        for (int j = 0; j < 4; ++j) {
          float val = cbb + 2.0f * acc4[i][j][r] - nns[j];
          rs += fmaxf(val, 0.0f);
        }
        lsum += mf * rs;
      }
    }
    lsum = wave_reduce_sum(lsum);
    __syncthreads();
    if (lane == 0) red[wave] = lsum;
    __syncthreads();
    if (tid == 0) atomicAdd(acc + 0, red[0] + red[1] + red[2] + red[3]);
  } else if (seg == 1) {
    // ortho: sum (gram - I)^2; diagonal computed exactly from f32 fn2
    float lsum = 0.0f;
    #pragma unroll
    for (int i = 0; i < 4; ++i) {
      #pragma unroll
      for (int r = 0; r < 4; ++r) {
        int gi = r0 + wy * 64 + i * 16 + (lane >> 4) * 4 + r;
        #pragma unroll
        for (int j = 0; j < 4; ++j) {
          int gj = c0 + wx * 64 + j * 16 + (lane & 15);
          float s = (gi == gj) ? (fn2[gi] - 1.0f) : acc4[i][j][r];
          lsum += s * s;
        }
      }
    }
    lsum = wave_reduce_sum(lsum);
    __syncthreads();
    if (lane == 0) red[wave] = lsum;
    __syncthreads();
    if (tid == 0) atomicAdd(acc + 2, red[0] + red[1] + red[2] + red[3]);
  } else {
    // W tile (rows of vhat x rows of F) + jt gather; each (b,t) term owned by
    // the block whose col range contains seli[b][t].
    float* Wt = (float*)smem;  // 32 x 128 f32 = 16 KB
    const int quad = lane >> 4, col15 = lane & 15;
    const int rl = tid >> 3;   // 0..31
    const int t8 = tid & 7;    // 0..7
    float jts = 0.0f;
    #pragma unroll
    for (int i = 0; i < 4; ++i) {
      __syncthreads();  // protect smem reuse (GEMM frags / previous pass)
      #pragma unroll
      for (int r = 0; r < 4; ++r) {
        int row_local = wy * 16 + quad * 4 + r;
        #pragma unroll
        for (int j = 0; j < 4; ++j)
          Wt[row_local * 128 + wx * 64 + j * 16 + col15] = acc4[i][j][r];
      }
      __syncthreads();
      // 256 (row,t) lookups for the 32 rows in this pass
      int b = r0 + (rl & 15) + i * 16 + (rl >> 4) * 64;
      int idx = seli[(size_t)b * 8 + t8];
      int c = idx - c0;
      if ((unsigned)c < 128u) {
        float w = Wt[rl * 128 + c];
        float term = selc[(size_t)b * 8 + t8] + 2.0f * w - fn2[idx];
        float mf = (mask[b] != 0) ? 1.0f : 0.0f;
        jts += mf * fmaxf(term, 0.0f);
      }
    }
    jts = wave_reduce_sum(jts);
    __syncthreads();
    if (lane == 0) red[wave] = jts;
    __syncthreads();
    if (tid == 0) atomicAdd(acc + 1, red[0] + red[1] + red[2] + red[3]);
    // msum: blocks owning c0==0 cover disjoint 128-row strips
    if (c0 == 0 && wave == 0) {
      float m = ((mask[r0 + lane] != 0) ? 1.0f : 0.0f) +
                ((mask[r0 + 64 + lane] != 0) ? 1.0f : 0.0f);
      m = wave_reduce_sum(m);
      if (lane == 0) atomicAdd(acc + 3, m);
    }
  }

  // last-block-done: combine and write output
  __threadfence();
  if (tid == 0) {
    unsigned old = atomicAdd((unsigned int*)(acc + 4), 1u);
    if (old == MAIN_BLOCKS - 1) {
      float ju = atomicAdd(acc + 0, 0.0f);
      float jt = atomicAdd(acc + 1, 0.0f);
      float oo = atomicAdd(acc + 2, 0.0f);
      float ms = atomicAdd(acc + 3, 0.0f);
      float Ju = (ms == 0.0f) ? 0.0f : ju / ((float)N_N * ms);
      float Jt = (ms == 0.0f) ? 0.0f : jt / ms;
      out[0] = Ju + Jt + 1.0e-3f * oo;
    }
  }
}

extern "C" void kernel_launch(void* const* d_in, const int* in_sizes, int n_in,
                              void* d_out, int out_size, void* d_ws, size_t ws_size,
                              hipStream_t stream) {
  (void)in_sizes; (void)n_in; (void)out_size; (void)ws_size;
  const float* v    = (const float*)d_in[0];
  const float* vhat = (const float*)d_in[1];
  const float* g    = (const float*)d_in[2];
  const float* F    = (const float*)d_in[3];
  const float* neg  = (const float*)d_in[4];
  const int*   mask = (const int*)d_in[5];

  float* ws = (float*)d_ws;
  float* acc  = ws;
  float* cb   = ws + 16;
  float* nn2  = ws + 8208;
  float* fn2  = ws + 10256;
  float* selc = ws + 10768;
  int*   seli = (int*)(ws + 76304);
  unsigned short* vhat_bf = (unsigned short*)(ws + 141840);
  unsigned short* neg_bf  = vhat_bf + (size_t)B_N * D_N;
  unsigned short* F_bf    = neg_bf + (size_t)N_N * D_N;

  prep_kernel<<<(B_N + N_N + K_N) / 4, 256, 0, stream>>>(
      v, vhat, neg, F, g, vhat_bf, neg_bf, F_bf, cb, nn2, fn2, selc, seli, acc);
  main_kernel<<<MAIN_BLOCKS, 256, 0, stream>>>(
      vhat_bf, neg_bf, F_bf, cb, nn2, fn2, mask, selc, seli, acc,
      (float*)d_out);
}

// Round 8
// 115.864 us; speedup vs baseline: 1.6344x; 1.6344x over previous
//
#include <hip/hip_runtime.h>

// Problem constants (fixed by reference setup_inputs)
#define B_N 8192
#define D_N 256
#define N_N 2048
#define K_N 512
#define T_N 8

using short8  = __attribute__((ext_vector_type(8))) short;
using floatx4 = __attribute__((ext_vector_type(4))) float;

// ---------------------------------------------------------------------------
// Workspace layout (float units):
//  cb        = ws + 0      [8192]
//  nn2       = ws + 8192   [2048]
//  fn2       = ws + 10240  [512]
//  ju_part   = ws + 10752  [1024]
//  jt_part   = ws + 11776  [256]
//  or_part   = ws + 12032  [16]
//  msum_part = ws + 12048  [32]
//  selc      = ws + 12080  [8192*8]
//  seli      = (int*)(ws + 77616)  [8192*8]
//  vhat_bf   = (ushort*)(ws + 143152)  [8192*256]  (16B aligned)
//  neg_bf    = vhat_bf + 8192*256      [2048*256]
//  F_bf      = neg_bf + 2048*256       [512*256]
// ---------------------------------------------------------------------------

__device__ __forceinline__ float wave_reduce_sum(float x) {
  #pragma unroll
  for (int off = 32; off > 0; off >>= 1) x += __shfl_down(x, off, 64);
  return x;
}

__device__ __forceinline__ unsigned int f2bf(float x) {
  unsigned u = __float_as_uint(x);
  return (u + 0x7fffu + ((u >> 16) & 1u)) >> 16;
}

__device__ __forceinline__ unsigned int pack2bf(float x, float y) {
  return f2bf(x) | (f2bf(y) << 16);
}

// async global->LDS, 16 bytes per lane; LDS dest is wave-uniform base + lane*16
__device__ __forceinline__ void gload16(const unsigned short* g, unsigned short* l) {
  __builtin_amdgcn_global_load_lds(
      (const __attribute__((address_space(1))) unsigned int*)g,
      (__attribute__((address_space(3))) unsigned int*)l, 16, 0, 0);
}

// compare-swap keeping (val,idx) pairs together
#define CSWAP(a, b)                                              \
  {                                                              \
    bool sw_ = sv[a] > sv[b];                                    \
    float tv_ = sw_ ? sv[a] : sv[b];                             \
    sv[a] = sw_ ? sv[b] : sv[a];                                 \
    sv[b] = tv_;                                                 \
    int ti_ = sw_ ? si[a] : si[b];                               \
    si[a] = sw_ ? si[b] : si[a];                                 \
    si[b] = ti_;                                                 \
  }

// --- prep: stats + bf16 conversion + bottom-8 selection + msum strips -------
// one row per wave; rows [0,B)=vhat(+v,+g-selection), [B,B+N)=neg, [B+N,..)=F
__global__ __launch_bounds__(256) void prep_kernel(
    const float* __restrict__ v, const float* __restrict__ vhat,
    const float* __restrict__ neg, const float* __restrict__ F,
    const float* __restrict__ g, const int* __restrict__ mask,
    unsigned short* __restrict__ vhat_bf, unsigned short* __restrict__ neg_bf,
    unsigned short* __restrict__ F_bf,
    float* __restrict__ cb, float* __restrict__ nn2, float* __restrict__ fn2,
    float* __restrict__ selc, int* __restrict__ seli,
    float* __restrict__ msum_part) {
  int lane = threadIdx.x & 63;
  int wave = threadIdx.x >> 6;
  int row = (blockIdx.x << 2) + wave;
  // msum strips: blocks 0..31 each sum 256 mask entries (block-uniform branch)
  if (blockIdx.x < 32) {
    float m = (mask[blockIdx.x * 256 + threadIdx.x] != 0) ? 1.0f : 0.0f;
    m = wave_reduce_sum(m);
    __shared__ float mred[4];
    if (lane == 0) mred[wave] = m;
    __syncthreads();
    if (threadIdx.x == 0)
      msum_part[blockIdx.x] = mred[0] + mred[1] + mred[2] + mred[3];
  }
  if (row < B_N) {
    const float4 a = *(const float4*)(vhat + (size_t)row * D_N + lane * 4);
    const float4 b = *(const float4*)(v + (size_t)row * D_N + lane * 4);
    float dx = a.x - b.x, dy = a.y - b.y, dz = a.z - b.z, dw = a.w - b.w;
    float t = dx * dx + dy * dy + dz * dz + dw * dw;
    float n = a.x * a.x + a.y * a.y + a.z * a.z + a.w * a.w;
    uint2 p;
    p.x = pack2bf(a.x, a.y);
    p.y = pack2bf(a.z, a.w);
    *(uint2*)(vhat_bf + (size_t)row * D_N + lane * 4) = p;
    t = wave_reduce_sum(t);
    n = wave_reduce_sum(n);
    if (lane == 0) cb[row] = 1.0f + t - n;
    // ---- bottom-8-of-512 selection on g[row] ----
    const float* grow = g + (size_t)row * K_N;
    float sv[8];
    int si[8];
    {
      float4 g0 = *(const float4*)(grow + lane * 8);
      float4 g1 = *(const float4*)(grow + lane * 8 + 4);
      sv[0] = g0.x; sv[1] = g0.y; sv[2] = g0.z; sv[3] = g0.w;
      sv[4] = g1.x; sv[5] = g1.y; sv[6] = g1.z; sv[7] = g1.w;
      #pragma unroll
      for (int j = 0; j < 8; ++j) si[j] = lane * 8 + j;
    }
    // Batcher odd-even mergesort, n=8 (19 comparators) -> ascending
    CSWAP(0,1) CSWAP(2,3) CSWAP(4,5) CSWAP(6,7)
    CSWAP(0,2) CSWAP(1,3) CSWAP(4,6) CSWAP(5,7)
    CSWAP(1,2) CSWAP(5,6)
    CSWAP(0,4) CSWAP(1,5) CSWAP(2,6) CSWAP(3,7)
    CSWAP(2,4) CSWAP(3,5)
    CSWAP(1,2) CSWAP(3,4) CSWAP(5,6)
    // 6 butterfly merge rounds: keep lowest 8 of (mine ++ partner)
    #pragma unroll
    for (int rr = 0; rr < 6; ++rr) {
      const int msk = 1 << rr;
      float pv[8];
      int pi[8];
      #pragma unroll
      for (int j = 0; j < 8; ++j) {
        pv[j] = __shfl_xor(sv[j], msk, 64);
        pi[j] = __shfl_xor(si[j], msk, 64);
      }
      float cv[8];
      int ci[8];
      #pragma unroll
      for (int j = 0; j < 8; ++j) {
        bool mine = sv[j] <= pv[7 - j];
        cv[j] = mine ? sv[j] : pv[7 - j];
        ci[j] = mine ? si[j] : pi[7 - j];
      }
      #pragma unroll
      for (int j = 0; j < 8; ++j) { sv[j] = cv[j]; si[j] = ci[j]; }
      // bitonic -> sorted (distances 4,2,1)
      CSWAP(0,4) CSWAP(1,5) CSWAP(2,6) CSWAP(3,7)
      CSWAP(0,2) CSWAP(1,3) CSWAP(4,6) CSWAP(5,7)
      CSWAP(0,1) CSWAP(2,3) CSWAP(4,5) CSWAP(6,7)
    }
    // every lane now holds the global bottom-8 (sorted).
    float gsum = 1e-10f;
    #pragma unroll
    for (int t8 = 0; t8 < T_N; ++t8) gsum += sv[t8];
    if (lane == 0) {
      float base = t - n;  // td - vn2 (valid on lane 0)
      #pragma unroll
      for (int t8 = 0; t8 < T_N; ++t8) {
        float gt = sv[t8] / gsum;
        float mt = (1.0f - gt) * (1.0f - gt);
        selc[(size_t)row * T_N + t8] = mt + base;
        seli[(size_t)row * T_N + t8] = si[t8];
      }
    }
  } else if (row < B_N + N_N) {
    int r = row - B_N;
    const float4 a = *(const float4*)(neg + (size_t)r * D_N + lane * 4);
    float n = a.x * a.x + a.y * a.y + a.z * a.z + a.w * a.w;
    uint2 p;
    p.x = pack2bf(a.x, a.y);
    p.y = pack2bf(a.z, a.w);
    *(uint2*)(neg_bf + (size_t)r * D_N + lane * 4) = p;
    n = wave_reduce_sum(n);
    if (lane == 0) nn2[r] = n;
  } else {
    int r = row - (B_N + N_N);
    const float4 a = *(const float4*)(F + (size_t)r * D_N + lane * 4);
    float n = a.x * a.x + a.y * a.y + a.z * a.z + a.w * a.w;
    uint2 p;
    p.x = pack2bf(a.x, a.y);
    p.y = pack2bf(a.z, a.w);
    *(uint2*)(F_bf + (size_t)r * D_N + lane * 4) = p;
    n = wave_reduce_sum(n);
    if (lane == 0) fn2[r] = n;
  }
}

// --- main: ju tiles [0,1024) | ortho [1024,1040) | W+jt-gather [1040,1296) --
__global__ __launch_bounds__(256) void main_kernel(
    const unsigned short* __restrict__ vhat_bf, const unsigned short* __restrict__ neg_bf,
    const unsigned short* __restrict__ F_bf,
    const float* __restrict__ cb, const float* __restrict__ nn2,
    const float* __restrict__ fn2, const int* __restrict__ mask,
    const float* __restrict__ selc, const int* __restrict__ seli,
    float* __restrict__ ju_part, float* __restrict__ or_part,
    float* __restrict__ jt_part) {
  __shared__ __align__(16) unsigned char smem[16384];
  const int bx = blockIdx.x;
  const int tid = threadIdx.x;
  const int lane = tid & 63;
  const int wave = tid >> 6;

  unsigned short* AsU = (unsigned short*)smem;  // 128 rows x 32 k (bf16)
  unsigned short* BsU = AsU + 4096;
  int r0, c0;
  const unsigned short *Abase, *Bbase;
  int seg;  // 0=ju 1=ortho 2=W+jt
  if (bx < 1024) {
    seg = 0;
    r0 = (bx >> 4) * 128;
    c0 = (bx & 15) * 128;
    Abase = vhat_bf;
    Bbase = neg_bf;
  } else if (bx < 1040) {
    seg = 1;
    int o = bx - 1024;
    r0 = (o >> 2) * 128;
    c0 = (o & 3) * 128;
    Abase = F_bf;
    Bbase = F_bf;
  } else {
    seg = 2;
    int o = bx - 1040;
    r0 = (o >> 2) * 128;
    c0 = (o & 3) * 128;
    Abase = vhat_bf;
    Bbase = F_bf;
  }
  const int wx = wave & 1, wy = wave >> 1;

  // staging: LDS slot (r, c_slot) holds global 16B-chunk c_g = c_slot ^ ((r>>1)&3)
  const int c_slot = lane & 3;
  const int rA0 = wave * 32 + (lane >> 2);
  const int rA1 = rA0 + 16;
  const int cg0 = c_slot ^ ((rA0 >> 1) & 3);
  const int cg1 = c_slot ^ ((rA1 >> 1) & 3);
  const unsigned short* gA0 = Abase + (size_t)(r0 + rA0) * D_N + cg0 * 8;
  const unsigned short* gA1 = Abase + (size_t)(r0 + rA1) * D_N + cg1 * 8;
  const unsigned short* gB0 = Bbase + (size_t)(c0 + rA0) * D_N + cg0 * 8;
  const unsigned short* gB1 = Bbase + (size_t)(c0 + rA1) * D_N + cg1 * 8;
  unsigned short* lA0 = AsU + wave * 1024 + lane * 8;
  unsigned short* lA1 = lA0 + 512;
  unsigned short* lB0 = BsU + wave * 1024 + lane * 8;
  unsigned short* lB1 = lB0 + 512;

  // fragment LDS offsets (constant over k-loop)
  const int fr = lane & 15;
  const int fc = lane >> 4;
  int aoff[4], boff[4];
  #pragma unroll
  for (int i = 0; i < 4; ++i) {
    int ra = wy * 64 + i * 16 + fr;
    aoff[i] = ra * 32 + (fc ^ ((ra >> 1) & 3)) * 8;
    int rb = wx * 64 + i * 16 + fr;
    boff[i] = rb * 32 + (fc ^ ((rb >> 1) & 3)) * 8;
  }

  floatx4 acc[4][4];
  #pragma unroll
  for (int i = 0; i < 4; ++i)
    #pragma unroll
    for (int j = 0; j < 4; ++j)
      acc[i][j] = floatx4{0.0f, 0.0f, 0.0f, 0.0f};

  for (int k0 = 0; k0 < D_N; k0 += 32) {
    __syncthreads();
    gload16(gA0 + k0, lA0);
    gload16(gA1 + k0, lA1);
    gload16(gB0 + k0, lB0);
    gload16(gB1 + k0, lB1);
    __syncthreads();
    short8 af[4], bf[4];
    #pragma unroll
    for (int i = 0; i < 4; ++i) af[i] = *(const short8*)(AsU + aoff[i]);
    #pragma unroll
    for (int j = 0; j < 4; ++j) bf[j] = *(const short8*)(BsU + boff[j]);
    #pragma unroll
    for (int i = 0; i < 4; ++i)
      #pragma unroll
      for (int j = 0; j < 4; ++j)
        acc[i][j] = __builtin_amdgcn_mfma_f32_16x16x32_bf16(af[i], bf[j], acc[i][j], 0, 0, 0);
  }

  // epilogue: C/D layout col=lane&15 (j), row=(lane>>4)*4+reg (i)
  float* red = (float*)smem;
  if (seg == 0) {
    float nns[4];
    #pragma unroll
    for (int j = 0; j < 4; ++j)
      nns[j] = nn2[c0 + wx * 64 + j * 16 + (lane & 15)];
    float lsum = 0.0f;
    #pragma unroll
    for (int i = 0; i < 4; ++i) {
      #pragma unroll
      for (int r = 0; r < 4; ++r) {
        int b = r0 + wy * 64 + i * 16 + (lane >> 4) * 4 + r;
        float cbb = cb[b];
        float mf = (mask[b] != 0) ? 1.0f : 0.0f;
        float rs = 0.0f;
        #pragma unroll
        for (int j = 0; j < 4; ++j) {
          float val = cbb + 2.0f * acc[i][j][r] - nns[j];
          rs += fmaxf(val, 0.0f);
        }
        lsum += mf * rs;
      }
    }
    lsum = wave_reduce_sum(lsum);
    __syncthreads();
    if (lane == 0) red[wave] = lsum;
    __syncthreads();
    if (tid == 0) ju_part[bx] = red[0] + red[1] + red[2] + red[3];
  } else if (seg == 1) {
    // ortho: sum (gram - I)^2; diagonal computed exactly from f32 fn2
    float lsum = 0.0f;
    #pragma unroll
    for (int i = 0; i < 4; ++i) {
      #pragma unroll
      for (int r = 0; r < 4; ++r) {
        int gi = r0 + wy * 64 + i * 16 + (lane >> 4) * 4 + r;
        #pragma unroll
        for (int j = 0; j < 4; ++j) {
          int gj = c0 + wx * 64 + j * 16 + (lane & 15);
          float s = (gi == gj) ? (fn2[gi] - 1.0f) : acc[i][j][r];
          lsum += s * s;
        }
      }
    }
    lsum = wave_reduce_sum(lsum);
    __syncthreads();
    if (lane == 0) red[wave] = lsum;
    __syncthreads();
    if (tid == 0) or_part[bx - 1024] = red[0] + red[1] + red[2] + red[3];
  } else {
    // W tile (rows of vhat x rows of F) + jt gather; each (b,t) term owned by
    // the block whose col range contains seli[b][t].
    float* Wt = (float*)smem;  // 32 x 128 f32 = 16 KB
    const int quad = lane >> 4, col15 = lane & 15;
    const int rl = tid >> 3;   // 0..31
    const int t8 = tid & 7;    // 0..7
    float jts = 0.0f;
    #pragma unroll
    for (int i = 0; i < 4; ++i) {
      __syncthreads();  // protect smem reuse (GEMM frags / previous pass)
      #pragma unroll
      for (int r = 0; r < 4; ++r) {
        int row_local = wy * 16 + quad * 4 + r;
        #pragma unroll
        for (int j = 0; j < 4; ++j)
          Wt[row_local * 128 + wx * 64 + j * 16 + col15] = acc[i][j][r];
      }
      __syncthreads();
      // 256 (row,t) lookups for the 32 rows in this pass
      int b = r0 + (rl & 15) + i * 16 + (rl >> 4) * 64;
      int idx = seli[(size_t)b * 8 + t8];
      int c = idx - c0;
      if ((unsigned)c < 128u) {
        float w = Wt[rl * 128 + c];
        float term = selc[(size_t)b * 8 + t8] + 2.0f * w - fn2[idx];
        float mf = (mask[b] != 0) ? 1.0f : 0.0f;
        jts += mf * fmaxf(term, 0.0f);
      }
    }
    jts = wave_reduce_sum(jts);
    __syncthreads();
    if (lane == 0) red[wave] = jts;
    __syncthreads();
    if (tid == 0) jt_part[bx - 1040] = red[0] + red[1] + red[2] + red[3];
  }
}

// --- finalize: sum small partial arrays, compute output ---------------------
__global__ __launch_bounds__(256) void finalize_kernel(
    const float* __restrict__ jt_part, const float* __restrict__ ju_part,
    const float* __restrict__ or_part, const float* __restrict__ msum_part,
    float* __restrict__ out) {
  int tid = threadIdx.x;
  float sjt = 0.0f, sju = 0.0f, sor = 0.0f, sm = 0.0f;
  for (int i = tid; i < 1024; i += 256) sju += ju_part[i];
  if (tid < 256) sjt = jt_part[tid];
  if (tid < 16) sor = or_part[tid];
  if (tid < 32) sm = msum_part[tid];
  sjt = wave_reduce_sum(sjt);
  sju = wave_reduce_sum(sju);
  sor = wave_reduce_sum(sor);
  sm  = wave_reduce_sum(sm);
  __shared__ float red[4][4];
  int lane = tid & 63, w = tid >> 6;
  if (lane == 0) {
    red[w][0] = sjt; red[w][1] = sju; red[w][2] = sor; red[w][3] = sm;
  }
  __syncthreads();
  if (tid == 0) {
    float jt = red[0][0] + red[1][0] + red[2][0] + red[3][0];
    float ju = red[0][1] + red[1][1] + red[2][1] + red[3][1];
    float oo = red[0][2] + red[1][2] + red[2][2] + red[3][2];
    float ms = red[0][3] + red[1][3] + red[2][3] + red[3][3];
    float Ju = (ms == 0.0f) ? 0.0f : ju / ((float)N_N * ms);
    float Jt = (ms == 0.0f) ? 0.0f : jt / ms;
    out[0] = Ju + Jt + 1.0e-3f * oo;
  }
}

extern "C" void kernel_launch(void* const* d_in, const int* in_sizes, int n_in,
                              void* d_out, int out_size, void* d_ws, size_t ws_size,
                              hipStream_t stream) {
  (void)in_sizes; (void)n_in; (void)out_size; (void)ws_size;
  const float* v    = (const float*)d_in[0];
  const float* vhat = (const float*)d_in[1];
  const float* g    = (const float*)d_in[2];
  const float* F    = (const float*)d_in[3];
  const float* neg  = (const float*)d_in[4];
  const int*   mask = (const int*)d_in[5];

  float* ws = (float*)d_ws;
  float* cb        = ws;
  float* nn2       = ws + 8192;
  float* fn2       = ws + 10240;
  float* ju_part   = ws + 10752;
  float* jt_part   = ws + 11776;
  float* or_part   = ws + 12032;
  float* msum_part = ws + 12048;
  float* selc      = ws + 12080;
  int*   seli      = (int*)(ws + 77616);
  unsigned short* vhat_bf = (unsigned short*)(ws + 143152);
  unsigned short* neg_bf  = vhat_bf + (size_t)B_N * D_N;
  unsigned short* F_bf    = neg_bf + (size_t)N_N * D_N;

  prep_kernel<<<(B_N + N_N + K_N) / 4, 256, 0, stream>>>(
      v, vhat, neg, F, g, mask, vhat_bf, neg_bf, F_bf, cb, nn2, fn2,
      selc, seli, msum_part);
  main_kernel<<<1024 + 16 + 256, 256, 0, stream>>>(
      vhat_bf, neg_bf, F_bf, cb, nn2, fn2, mask, selc, seli,
      ju_part, or_part, jt_part);
  finalize_kernel<<<1, 256, 0, stream>>>(jt_part, ju_part, or_part, msum_part,
                                         (float*)d_out);
}